// Round 3
// baseline (209.148 us; speedup 1.0000x reference)
//
#include <hip/hip_runtime.h>
#include <hip/hip_bf16.h>
#include <cstdint>
#include <cstddef>

// AFT forward, MI355X. Pipeline:
//  1. cvt   : data f32 -> bf16 (row-major [4096][1024], K contiguous)
//  2. cvt+exp: pos_bias f32 -> P=exp(pb) bf16 [1024][1024] (A of GEMM2)
//  3. tconv : W_qkv [1024][3072] -> WqkvT bf16 [3072][1024]  (B^T layout)
//  4. tconv : W_out [1024][1024] -> WoutT bf16 [1024][1024]
//  5. GEMM1 : qkv f32 [4096][3072] = data_bf @ WqkvT^T + b_qkv
//  6. E1    : BndT bf16 [8192][1024]; rows [0,4096)= (exp(k)*v)^T, [4096,8192)= exp(k)^T
//  7. GEMM2 : Cnd f32 [1024][8192] = P @ BndT^T   (num | den)
//  8. E2    : Y bf16 [4096][1024] = sigmoid(q) * num / den   (Y aliases data_bf)
//  9. GEMM3 : out f32 [4096][1024] = Y @ WoutT^T + b_out
// GEMM = m97 structure: 128x128 tile, BK=32, 4 waves, mfma_f32_16x16x32_bf16,
// global_load_lds width-16 staging, linear LDS (T2 swizzle null in this regime).
// Workspace peak: 114 MB (Y aliased onto data_bf).

typedef __bf16 bf16_t;
typedef __attribute__((ext_vector_type(8))) __bf16 bf16x8;
typedef __attribute__((ext_vector_type(4))) __bf16 bf16x4;
typedef __attribute__((ext_vector_type(4))) float floatx4;

#define T_DIM 1024
#define B_DIM 4
#define D_DIM 1024
#define R_DIM (T_DIM * B_DIM)   // 4096
#define N_QKV (3 * D_DIM)       // 3072
#define N_ND  (2 * R_DIM)       // 8192

// ---------------- elementwise convert (optionally exp) ----------------
__global__ void k_cvt(const float* __restrict__ in, bf16_t* __restrict__ out,
                      int n, int do_exp) {
    int i = (blockIdx.x * blockDim.x + threadIdx.x) * 4;
    if (i >= n) return;
    float4 v = *reinterpret_cast<const float4*>(in + i);
    bf16x4 o;
    if (do_exp) {
        o[0] = (bf16_t)__expf(v.x); o[1] = (bf16_t)__expf(v.y);
        o[2] = (bf16_t)__expf(v.z); o[3] = (bf16_t)__expf(v.w);
    } else {
        o[0] = (bf16_t)v.x; o[1] = (bf16_t)v.y;
        o[2] = (bf16_t)v.z; o[3] = (bf16_t)v.w;
    }
    *reinterpret_cast<bf16x4*>(out + i) = o;
}

// ---------------- transpose + convert: in[K][N] f32 -> out[N][K] bf16 ----------------
__global__ void k_tconv(const float* __restrict__ in, bf16_t* __restrict__ out,
                        int K, int N) {
    __shared__ float s[32][33];
    int n0 = blockIdx.x * 32, k0 = blockIdx.y * 32;
    int tx = threadIdx.x & 31, ty = threadIdx.x >> 5;  // 32 x 8
#pragma unroll
    for (int i = 0; i < 4; ++i)
        s[ty + i * 8][tx] = in[(size_t)(k0 + ty + i * 8) * N + n0 + tx];
    __syncthreads();
#pragma unroll
    for (int i = 0; i < 4; ++i)
        out[(size_t)(n0 + ty + i * 8) * K + k0 + tx] = (bf16_t)s[tx][ty + i * 8];
}

// ---------------- E1: qkv -> [EKV | EK]^T bf16 ----------------
__global__ void k_e1(const float* __restrict__ qkv, bf16_t* __restrict__ BndT) {
    __shared__ float sk[32][33], sv[32][33];
    int j0 = blockIdx.x * 32, d0 = blockIdx.y * 32, b = blockIdx.z;
    int tx = threadIdx.x & 31, ty = threadIdx.x >> 5;
#pragma unroll
    for (int i = 0; i < 4; ++i) {
        int j = j0 + ty + i * 8;
        size_t base = (size_t)j * (B_DIM * N_QKV) + (size_t)b * N_QKV;
        float kk = qkv[base + D_DIM + d0 + tx];
        float vv = qkv[base + 2 * D_DIM + d0 + tx];
        float e = __expf(kk);
        sk[ty + i * 8][tx] = e;
        sv[ty + i * 8][tx] = e * vv;
    }
    __syncthreads();
#pragma unroll
    for (int i = 0; i < 4; ++i) {
        int d = d0 + ty + i * 8;
        int r = b * D_DIM + d;
        BndT[(size_t)r * T_DIM + j0 + tx] = (bf16_t)sv[tx][ty + i * 8];
        BndT[(size_t)(R_DIM + r) * T_DIM + j0 + tx] = (bf16_t)sk[tx][ty + i * 8];
    }
}

// ---------------- E2: Y = sigmoid(q) * num / den (4 elems/thread) ----------------
__global__ void k_e2(const float* __restrict__ qkv, const float* __restrict__ Cnd,
                     bf16_t* __restrict__ Y) {
    int idx = (blockIdx.x * blockDim.x + threadIdx.x) * 4;  // over T*B*D
    int d = idx & (D_DIM - 1);
    int b = (idx >> 10) & 3;
    int t = idx >> 12;
    float4 q   = *reinterpret_cast<const float4*>(
        qkv + (size_t)t * (B_DIM * N_QKV) + (size_t)b * N_QKV + d);
    float4 num = *reinterpret_cast<const float4*>(
        Cnd + (size_t)t * N_ND + b * D_DIM + d);
    float4 den = *reinterpret_cast<const float4*>(
        Cnd + (size_t)t * N_ND + R_DIM + b * D_DIM + d);
    bf16x4 o;
    o[0] = (bf16_t)(num.x / (den.x * (1.0f + __expf(-q.x))));
    o[1] = (bf16_t)(num.y / (den.y * (1.0f + __expf(-q.y))));
    o[2] = (bf16_t)(num.z / (den.z * (1.0f + __expf(-q.z))));
    o[3] = (bf16_t)(num.w / (den.w * (1.0f + __expf(-q.w))));
    *reinterpret_cast<bf16x4*>(Y + idx) = o;
}

// ---------------- GEMM: C[M][N] = A[M][K] @ BT[N][K]^T (+bias) ----------------
// m97 structure: 128x128 tile, BK=32, 256 thr (4 waves 2x2), 16x16x32 bf16 MFMA.
__global__ __launch_bounds__(256)
void k_gemm(const bf16_t* __restrict__ A, const bf16_t* __restrict__ BT,
            const float* __restrict__ bias, float* __restrict__ C,
            int M, int N, int K) {
    __shared__ __align__(16) bf16_t As[128 * 32];
    __shared__ __align__(16) bf16_t Bs[128 * 32];
    const int tid = threadIdx.x;
    const int wid = tid >> 6, lane = tid & 63;
    const int wm = wid >> 1, wn = wid & 1;
    const int row0 = blockIdx.x * 128, col0 = blockIdx.y * 128;

    floatx4 acc[4][4];
#pragma unroll
    for (int m = 0; m < 4; ++m)
#pragma unroll
        for (int n = 0; n < 4; ++n) acc[m][n] = (floatx4){0.f, 0.f, 0.f, 0.f};

    const int lr = lane & 15;
    const int kq = (lane >> 4) * 8;

    // staging: thread covers elements e0 and e0+512 of the 4096-elem tile
    const int e0 = wid * 1024 + lane * 8;
    const int ra0 = e0 >> 5, kk0 = e0 & 31;
    const int ra1 = (e0 + 512) >> 5, kk1 = (e0 + 512) & 31;

    const bf16_t* Ab = A + (size_t)row0 * K;
    const bf16_t* Bb = BT + (size_t)col0 * K;

    for (int kt = 0; kt < K; kt += 32) {
        __syncthreads();
        __builtin_amdgcn_global_load_lds(
            (const __attribute__((address_space(1))) void*)(Ab + (size_t)ra0 * K + kt + kk0),
            (__attribute__((address_space(3))) void*)(As + wid * 1024), 16, 0, 0);
        __builtin_amdgcn_global_load_lds(
            (const __attribute__((address_space(1))) void*)(Ab + (size_t)ra1 * K + kt + kk1),
            (__attribute__((address_space(3))) void*)(As + wid * 1024 + 512), 16, 0, 0);
        __builtin_amdgcn_global_load_lds(
            (const __attribute__((address_space(1))) void*)(Bb + (size_t)ra0 * K + kt + kk0),
            (__attribute__((address_space(3))) void*)(Bs + wid * 1024), 16, 0, 0);
        __builtin_amdgcn_global_load_lds(
            (const __attribute__((address_space(1))) void*)(Bb + (size_t)ra1 * K + kt + kk1),
            (__attribute__((address_space(3))) void*)(Bs + wid * 1024 + 512), 16, 0, 0);
        __syncthreads();

        bf16x8 af[4], bfr[4];
#pragma unroll
        for (int m = 0; m < 4; ++m)
            af[m] = *reinterpret_cast<const bf16x8*>(As + (wm * 64 + m * 16 + lr) * 32 + kq);
#pragma unroll
        for (int n = 0; n < 4; ++n)
            bfr[n] = *reinterpret_cast<const bf16x8*>(Bs + (wn * 64 + n * 16 + lr) * 32 + kq);
#pragma unroll
        for (int m = 0; m < 4; ++m)
#pragma unroll
            for (int n = 0; n < 4; ++n)
                acc[m][n] = __builtin_amdgcn_mfma_f32_16x16x32_bf16(af[m], bfr[n], acc[m][n], 0, 0, 0);
    }

    // epilogue: C/D layout col=lane&15, row=(lane>>4)*4+j  [m89-verified]
    const int lg = lane >> 4;
#pragma unroll
    for (int n = 0; n < 4; ++n) {
        int col = col0 + wn * 64 + n * 16 + lr;
        float bv = bias ? bias[col] : 0.0f;
#pragma unroll
        for (int m = 0; m < 4; ++m) {
            int row = row0 + wm * 64 + m * 16 + lg * 4;
            float* Cp = C + (size_t)row * N + col;
#pragma unroll
            for (int j = 0; j < 4; ++j) Cp[(size_t)j * N] = acc[m][n][j] + bv;
        }
    }
}

extern "C" void kernel_launch(void* const* d_in, const int* in_sizes, int n_in,
                              void* d_out, int out_size, void* d_ws, size_t ws_size,
                              hipStream_t stream) {
    const float* data     = (const float*)d_in[0];  // [T,B,D]
    const float* W_qkv    = (const float*)d_in[1];  // [D,3D]
    const float* b_qkv    = (const float*)d_in[2];  // [3D]
    const float* pos_bias = (const float*)d_in[3];  // [T,T]
    const float* W_out    = (const float*)d_in[4];  // [D,D]
    const float* b_out    = (const float*)d_in[5];  // [D]
    float* out = (float*)d_out;

    char* ws = (char*)d_ws;
    const size_t MB = 1024 * 1024;
    bf16_t* data_bf = (bf16_t*)(ws + 0);         //  8 MB [4096][1024]
    bf16_t* WqkvT   = (bf16_t*)(ws + 8 * MB);    //  6 MB [3072][1024]
    bf16_t* WoutT   = (bf16_t*)(ws + 14 * MB);   //  2 MB [1024][1024]
    bf16_t* P_bf    = (bf16_t*)(ws + 16 * MB);   //  2 MB [1024][1024]
    float*  qkv     = (float*) (ws + 18 * MB);   // 48 MB [4096][3072]
    bf16_t* BndT    = (bf16_t*)(ws + 66 * MB);   // 16 MB [8192][1024]
    float*  Cnd     = (float*) (ws + 82 * MB);   // 32 MB [1024][8192]
    bf16_t* Y       = (bf16_t*)(ws + 0);         //  8 MB, aliases data_bf (dead after GEMM1)

    // 1. data -> bf16
    k_cvt<<<dim3(R_DIM * D_DIM / 1024), dim3(256), 0, stream>>>(data, data_bf, R_DIM * D_DIM, 0);
    // 2. P = exp(pos_bias) -> bf16
    k_cvt<<<dim3(T_DIM * T_DIM / 1024), dim3(256), 0, stream>>>(pos_bias, P_bf, T_DIM * T_DIM, 1);
    // 3. W_qkv^T -> bf16
    k_tconv<<<dim3(N_QKV / 32, D_DIM / 32), dim3(256), 0, stream>>>(W_qkv, WqkvT, D_DIM, N_QKV);
    // 4. W_out^T -> bf16
    k_tconv<<<dim3(D_DIM / 32, D_DIM / 32), dim3(256), 0, stream>>>(W_out, WoutT, D_DIM, D_DIM);
    // 5. qkv = data @ W_qkv + b_qkv
    k_gemm<<<dim3(R_DIM / 128, N_QKV / 128), dim3(256), 0, stream>>>(
        data_bf, WqkvT, b_qkv, qkv, R_DIM, N_QKV, D_DIM);
    // 6. E1: build [EKV | EK]^T
    k_e1<<<dim3(T_DIM / 32, D_DIM / 32, B_DIM), dim3(256), 0, stream>>>(qkv, BndT);
    // 7. Cnd = P @ [EKV | EK]
    k_gemm<<<dim3(T_DIM / 128, N_ND / 128), dim3(256), 0, stream>>>(
        P_bf, BndT, nullptr, Cnd, T_DIM, N_ND, T_DIM);
    // 8. E2: Y = sigmoid(q) * num / den
    k_e2<<<dim3(R_DIM * D_DIM / 1024), dim3(256), 0, stream>>>(qkv, Cnd, Y);
    // 9. out = Y @ W_out + b_out
    k_gemm<<<dim3(R_DIM / 128, D_DIM / 128), dim3(256), 0, stream>>>(
        Y, WoutT, b_out, out, R_DIM, D_DIM, D_DIM);
}

// Round 4
// 193.941 us; speedup vs baseline: 1.0784x; 1.0784x over previous
//
#include <hip/hip_runtime.h>
#include <hip/hip_bf16.h>
#include <cstdint>
#include <cstddef>

// AFT forward, MI355X. Pipeline (8 dispatches):
//  1. cvt   : data f32 -> bf16 [4096][1024]
//  2. cvt+exp: pos_bias f32 -> P=exp(pb) bf16 [1024][1024]
//  3. tconv : W_qkv -> WqkvT bf16 [3072][1024]
//  4. tconv : W_out -> WoutT bf16 [1024][1024]
//  5. GEMM1 : qkv f32 [4096][3072] = data_bf @ WqkvT^T + b_qkv        (m97 128^2)
//  6. E1    : BndT bf16 [8192][1024], rows in 32-groups [16 num | 16 den]:
//             rr = (r>>4)*32 + (r&15)      -> row rr    = (exp(k)*v)^T  (num)
//                                          -> row rr+16 = exp(k)^T      (den)
//             where r = b*1024 + d
//  7. GEMM2f: fused AFT epilogue: acc pair (n even / n odd) = num/den of the SAME
//             16 cols -> Y[t*4096+r] = sigmoid(q)*num/den, bf16. No Cnd buffer.
//  8. GEMM3 : out f32 [4096][1024] = Y @ WoutT^T + b_out
// GEMM = m97 structure: 128x128 tile, BK=32, 4 waves, mfma_f32_16x16x32_bf16,
// global_load_lds width-16 staging, linear LDS.
// Workspace peak: 82 MB (Y aliases data_bf, dead after GEMM1).

typedef __bf16 bf16_t;
typedef __attribute__((ext_vector_type(8))) __bf16 bf16x8;
typedef __attribute__((ext_vector_type(4))) __bf16 bf16x4;
typedef __attribute__((ext_vector_type(4))) float floatx4;

#define T_DIM 1024
#define B_DIM 4
#define D_DIM 1024
#define R_DIM (T_DIM * B_DIM)   // 4096
#define N_QKV (3 * D_DIM)       // 3072
#define N_ND  (2 * R_DIM)       // 8192

// ---------------- elementwise convert (optionally exp) ----------------
__global__ void k_cvt(const float* __restrict__ in, bf16_t* __restrict__ out,
                      int n, int do_exp) {
    int i = (blockIdx.x * blockDim.x + threadIdx.x) * 4;
    if (i >= n) return;
    float4 v = *reinterpret_cast<const float4*>(in + i);
    bf16x4 o;
    if (do_exp) {
        o[0] = (bf16_t)__expf(v.x); o[1] = (bf16_t)__expf(v.y);
        o[2] = (bf16_t)__expf(v.z); o[3] = (bf16_t)__expf(v.w);
    } else {
        o[0] = (bf16_t)v.x; o[1] = (bf16_t)v.y;
        o[2] = (bf16_t)v.z; o[3] = (bf16_t)v.w;
    }
    *reinterpret_cast<bf16x4*>(out + i) = o;
}

// ---------------- transpose + convert: in[K][N] f32 -> out[N][K] bf16 ----------------
__global__ void k_tconv(const float* __restrict__ in, bf16_t* __restrict__ out,
                        int K, int N) {
    __shared__ float s[32][33];
    int n0 = blockIdx.x * 32, k0 = blockIdx.y * 32;
    int tx = threadIdx.x & 31, ty = threadIdx.x >> 5;  // 32 x 8
#pragma unroll
    for (int i = 0; i < 4; ++i)
        s[ty + i * 8][tx] = in[(size_t)(k0 + ty + i * 8) * N + n0 + tx];
    __syncthreads();
#pragma unroll
    for (int i = 0; i < 4; ++i)
        out[(size_t)(n0 + ty + i * 8) * K + k0 + tx] = (bf16_t)s[tx][ty + i * 8];
}

// ---------------- E1: qkv -> interleaved [num|den] rows, bf16 ----------------
__global__ void k_e1(const float* __restrict__ qkv, bf16_t* __restrict__ BndT) {
    __shared__ float sk[32][33], sv[32][33];
    int j0 = blockIdx.x * 32, d0 = blockIdx.y * 32, b = blockIdx.z;
    int tx = threadIdx.x & 31, ty = threadIdx.x >> 5;
#pragma unroll
    for (int i = 0; i < 4; ++i) {
        int j = j0 + ty + i * 8;
        size_t base = (size_t)j * (B_DIM * N_QKV) + (size_t)b * N_QKV;
        float kk = qkv[base + D_DIM + d0 + tx];
        float vv = qkv[base + 2 * D_DIM + d0 + tx];
        float e = __expf(kk);
        sk[ty + i * 8][tx] = e;
        sv[ty + i * 8][tx] = e * vv;
    }
    __syncthreads();
#pragma unroll
    for (int i = 0; i < 4; ++i) {
        int d = d0 + ty + i * 8;
        int r = b * D_DIM + d;
        int rr = ((r >> 4) << 5) + (r & 15);   // 32-group: [16 num | 16 den]
        BndT[(size_t)rr * T_DIM + j0 + tx] = (bf16_t)sv[tx][ty + i * 8];        // num
        BndT[(size_t)(rr + 16) * T_DIM + j0 + tx] = (bf16_t)sk[tx][ty + i * 8]; // den
    }
}

// ---------------- GEMM: C[M][N] = A[M][K] @ BT[N][K]^T (+bias) ----------------
// m97 structure: 128x128 tile, BK=32, 256 thr (4 waves 2x2), 16x16x32 bf16 MFMA.
__global__ __launch_bounds__(256)
void k_gemm(const bf16_t* __restrict__ A, const bf16_t* __restrict__ BT,
            const float* __restrict__ bias, float* __restrict__ C,
            int M, int N, int K) {
    __shared__ __align__(16) bf16_t As[128 * 32];
    __shared__ __align__(16) bf16_t Bs[128 * 32];
    const int tid = threadIdx.x;
    const int wid = tid >> 6, lane = tid & 63;
    const int wm = wid >> 1, wn = wid & 1;
    const int row0 = blockIdx.x * 128, col0 = blockIdx.y * 128;

    floatx4 acc[4][4];
#pragma unroll
    for (int m = 0; m < 4; ++m)
#pragma unroll
        for (int n = 0; n < 4; ++n) acc[m][n] = (floatx4){0.f, 0.f, 0.f, 0.f};

    const int lr = lane & 15;
    const int kq = (lane >> 4) * 8;

    const int e0 = wid * 1024 + lane * 8;
    const int ra0 = e0 >> 5, kk0 = e0 & 31;
    const int ra1 = (e0 + 512) >> 5, kk1 = (e0 + 512) & 31;

    const bf16_t* Ab = A + (size_t)row0 * K;
    const bf16_t* Bb = BT + (size_t)col0 * K;

    for (int kt = 0; kt < K; kt += 32) {
        __syncthreads();
        __builtin_amdgcn_global_load_lds(
            (const __attribute__((address_space(1))) void*)(Ab + (size_t)ra0 * K + kt + kk0),
            (__attribute__((address_space(3))) void*)(As + wid * 1024), 16, 0, 0);
        __builtin_amdgcn_global_load_lds(
            (const __attribute__((address_space(1))) void*)(Ab + (size_t)ra1 * K + kt + kk1),
            (__attribute__((address_space(3))) void*)(As + wid * 1024 + 512), 16, 0, 0);
        __builtin_amdgcn_global_load_lds(
            (const __attribute__((address_space(1))) void*)(Bb + (size_t)ra0 * K + kt + kk0),
            (__attribute__((address_space(3))) void*)(Bs + wid * 1024), 16, 0, 0);
        __builtin_amdgcn_global_load_lds(
            (const __attribute__((address_space(1))) void*)(Bb + (size_t)ra1 * K + kt + kk1),
            (__attribute__((address_space(3))) void*)(Bs + wid * 1024 + 512), 16, 0, 0);
        __syncthreads();

        bf16x8 af[4], bfr[4];
#pragma unroll
        for (int m = 0; m < 4; ++m)
            af[m] = *reinterpret_cast<const bf16x8*>(As + (wm * 64 + m * 16 + lr) * 32 + kq);
#pragma unroll
        for (int n = 0; n < 4; ++n)
            bfr[n] = *reinterpret_cast<const bf16x8*>(Bs + (wn * 64 + n * 16 + lr) * 32 + kq);
#pragma unroll
        for (int m = 0; m < 4; ++m)
#pragma unroll
            for (int n = 0; n < 4; ++n)
                acc[m][n] = __builtin_amdgcn_mfma_f32_16x16x32_bf16(af[m], bfr[n], acc[m][n], 0, 0, 0);
    }

    // epilogue: C/D layout col=lane&15, row=(lane>>4)*4+j  [m89-verified]
    const int lg = lane >> 4;
#pragma unroll
    for (int n = 0; n < 4; ++n) {
        int col = col0 + wn * 64 + n * 16 + lr;
        float bv = bias ? bias[col] : 0.0f;
#pragma unroll
        for (int m = 0; m < 4; ++m) {
            int row = row0 + wm * 64 + m * 16 + lg * 4;
            float* Cp = C + (size_t)row * N + col;
#pragma unroll
            for (int j = 0; j < 4; ++j) Cp[(size_t)j * N] = acc[m][n][j] + bv;
        }
    }
}

// ---------------- GEMM2 fused: Cnd = P @ BndT^T, epilogue = sigmoid(q)*num/den ----------------
// Identical main loop; BndT's [16 num | 16 den] row-grouping makes fragment pairs
// (n=0,1) and (n=2,3) carry num/den for the SAME 16 output columns -> lane-local ratio.
// M=1024 (t), N=8192 (interleaved), K=1024.
__global__ __launch_bounds__(256)
void k_gemm_aft(const bf16_t* __restrict__ A, const bf16_t* __restrict__ BT,
                const float* __restrict__ qkv, bf16_t* __restrict__ Y) {
    const int M = T_DIM, N = N_ND, K = T_DIM;
    (void)M; (void)N;
    __shared__ __align__(16) bf16_t As[128 * 32];
    __shared__ __align__(16) bf16_t Bs[128 * 32];
    const int tid = threadIdx.x;
    const int wid = tid >> 6, lane = tid & 63;
    const int wm = wid >> 1, wn = wid & 1;
    const int row0 = blockIdx.x * 128, col0 = blockIdx.y * 128;

    floatx4 acc[4][4];
#pragma unroll
    for (int m = 0; m < 4; ++m)
#pragma unroll
        for (int n = 0; n < 4; ++n) acc[m][n] = (floatx4){0.f, 0.f, 0.f, 0.f};

    const int lr = lane & 15;
    const int kq = (lane >> 4) * 8;

    const int e0 = wid * 1024 + lane * 8;
    const int ra0 = e0 >> 5, kk0 = e0 & 31;
    const int ra1 = (e0 + 512) >> 5, kk1 = (e0 + 512) & 31;

    const bf16_t* Ab = A + (size_t)row0 * K;
    const bf16_t* Bb = BT + (size_t)col0 * K;

    for (int kt = 0; kt < K; kt += 32) {
        __syncthreads();
        __builtin_amdgcn_global_load_lds(
            (const __attribute__((address_space(1))) void*)(Ab + (size_t)ra0 * K + kt + kk0),
            (__attribute__((address_space(3))) void*)(As + wid * 1024), 16, 0, 0);
        __builtin_amdgcn_global_load_lds(
            (const __attribute__((address_space(1))) void*)(Ab + (size_t)ra1 * K + kt + kk1),
            (__attribute__((address_space(3))) void*)(As + wid * 1024 + 512), 16, 0, 0);
        __builtin_amdgcn_global_load_lds(
            (const __attribute__((address_space(1))) void*)(Bb + (size_t)ra0 * K + kt + kk0),
            (__attribute__((address_space(3))) void*)(Bs + wid * 1024), 16, 0, 0);
        __builtin_amdgcn_global_load_lds(
            (const __attribute__((address_space(1))) void*)(Bb + (size_t)ra1 * K + kt + kk1),
            (__attribute__((address_space(3))) void*)(Bs + wid * 1024 + 512), 16, 0, 0);
        __syncthreads();

        bf16x8 af[4], bfr[4];
#pragma unroll
        for (int m = 0; m < 4; ++m)
            af[m] = *reinterpret_cast<const bf16x8*>(As + (wm * 64 + m * 16 + lr) * 32 + kq);
#pragma unroll
        for (int n = 0; n < 4; ++n)
            bfr[n] = *reinterpret_cast<const bf16x8*>(Bs + (wn * 64 + n * 16 + lr) * 32 + kq);
#pragma unroll
        for (int m = 0; m < 4; ++m)
#pragma unroll
            for (int n = 0; n < 4; ++n)
                acc[m][n] = __builtin_amdgcn_mfma_f32_16x16x32_bf16(af[m], bfr[n], acc[m][n], 0, 0, 0);
    }

    // fused AFT epilogue
    const int lg = lane >> 4;
#pragma unroll
    for (int p = 0; p < 2; ++p) {
        int ncol = col0 + wn * 64 + p * 32 + lr;       // num column (fragment n=2p)
        int r = ((ncol >> 5) << 4) + lr;               // original r = b*1024 + d
        int b = r >> 10, d = r & (D_DIM - 1);
#pragma unroll
        for (int m = 0; m < 4; ++m) {
            int trow = row0 + wm * 64 + m * 16 + lg * 4;
#pragma unroll
            for (int j = 0; j < 4; ++j) {
                int t = trow + j;
                float num = acc[m][2 * p][j];
                float den = acc[m][2 * p + 1][j];
                float q = qkv[(size_t)t * (B_DIM * N_QKV) + (size_t)b * N_QKV + d];
                float y = num / (den * (1.0f + __expf(-q)));
                Y[(size_t)t * R_DIM + r] = (bf16_t)y;
            }
        }
    }
}

extern "C" void kernel_launch(void* const* d_in, const int* in_sizes, int n_in,
                              void* d_out, int out_size, void* d_ws, size_t ws_size,
                              hipStream_t stream) {
    const float* data     = (const float*)d_in[0];  // [T,B,D]
    const float* W_qkv    = (const float*)d_in[1];  // [D,3D]
    const float* b_qkv    = (const float*)d_in[2];  // [3D]
    const float* pos_bias = (const float*)d_in[3];  // [T,T]
    const float* W_out    = (const float*)d_in[4];  // [D,D]
    const float* b_out    = (const float*)d_in[5];  // [D]
    float* out = (float*)d_out;

    char* ws = (char*)d_ws;
    const size_t MB = 1024 * 1024;
    bf16_t* data_bf = (bf16_t*)(ws + 0);         //  8 MB [4096][1024]
    bf16_t* WqkvT   = (bf16_t*)(ws + 8 * MB);    //  6 MB [3072][1024]
    bf16_t* WoutT   = (bf16_t*)(ws + 14 * MB);   //  2 MB [1024][1024]
    bf16_t* P_bf    = (bf16_t*)(ws + 16 * MB);   //  2 MB [1024][1024]
    float*  qkv     = (float*) (ws + 18 * MB);   // 48 MB [4096][3072]
    bf16_t* BndT    = (bf16_t*)(ws + 66 * MB);   // 16 MB [8192][1024] interleaved
    bf16_t* Y       = (bf16_t*)(ws + 0);         //  8 MB, aliases data_bf (dead after GEMM1)

    // 1. data -> bf16
    k_cvt<<<dim3(R_DIM * D_DIM / 1024), dim3(256), 0, stream>>>(data, data_bf, R_DIM * D_DIM, 0);
    // 2. P = exp(pos_bias) -> bf16
    k_cvt<<<dim3(T_DIM * T_DIM / 1024), dim3(256), 0, stream>>>(pos_bias, P_bf, T_DIM * T_DIM, 1);
    // 3. W_qkv^T -> bf16
    k_tconv<<<dim3(N_QKV / 32, D_DIM / 32), dim3(256), 0, stream>>>(W_qkv, WqkvT, D_DIM, N_QKV);
    // 4. W_out^T -> bf16
    k_tconv<<<dim3(D_DIM / 32, D_DIM / 32), dim3(256), 0, stream>>>(W_out, WoutT, D_DIM, D_DIM);
    // 5. qkv = data @ W_qkv + b_qkv
    k_gemm<<<dim3(R_DIM / 128, N_QKV / 128), dim3(256), 0, stream>>>(
        data_bf, WqkvT, b_qkv, qkv, R_DIM, N_QKV, D_DIM);
    // 6. E1: build interleaved [num|den]^T
    k_e1<<<dim3(T_DIM / 32, D_DIM / 32, B_DIM), dim3(256), 0, stream>>>(qkv, BndT);
    // 7. GEMM2 fused: Y = sigmoid(q) * (P@EKV) / (P@EK)
    k_gemm_aft<<<dim3(T_DIM / 128, N_ND / 128), dim3(256), 0, stream>>>(
        P_bf, BndT, qkv, Y);
    // 8. out = Y @ W_out + b_out
    k_gemm<<<dim3(R_DIM / 128, D_DIM / 128), dim3(256), 0, stream>>>(
        Y, WoutT, b_out, out, R_DIM, D_DIM, D_DIM);
}